// Round 1
// baseline (29.586 us; speedup 1.0000x reference)
//
#include <hip/hip_runtime.h>

// y[b,o,h,w] = sum_j alphas[o,j] * x[b,j,(128-h)&127,(128-w)&127]
// (FFT2 -> complex channel mix -> IFFT2 collapses to flipped-input channel GEMM;
//  betas contributes only to the imaginary part and drops out.)

using bf16   = __bf16;
using bf16x4 = __attribute__((ext_vector_type(4))) __bf16;
using bf16x8 = __attribute__((ext_vector_type(8))) __bf16;
using f32x4  = __attribute__((ext_vector_type(4))) float;

#define LDSA_STRIDE 272            // bytes per alphas row: 128*2 + 16 pad (bank-conflict-free)
#define LDSA_BYTES  (128 * 272)    // 34816
#define LDSX_BYTES  (32 * 1024)    // 32768  (X4 layout: [k>>2][n*4 + (k&3)] bf16)

static __device__ __forceinline__ float f4c(const float4& v, int i) {
    switch (i) { case 0: return v.x; case 1: return v.y; case 2: return v.z; default: return v.w; }
}

__global__ __launch_bounds__(256, 2)
void kk_freqmix_kernel(const float* __restrict__ x,
                       const float* __restrict__ alphas,
                       float* __restrict__ out)
{
    __shared__ unsigned char lds[LDSA_BYTES + LDSX_BYTES];
    unsigned char* const ldsX = lds + LDSA_BYTES;

    const int t   = threadIdx.x;
    const int bid = blockIdx.x;
    const int b   = bid >> 7;     // batch
    const int h2  = bid & 127;    // input row (pre-flip)

    // ---- stage alphas (fp32 -> bf16) into LDS [o][j], row stride 272 B ----
    #pragma unroll
    for (int it = 0; it < 8; ++it) {
        const int ch  = it * 256 + t;
        const int o   = ch >> 4;
        const int oct = ch & 15;           // 8-element group within the row
        const float4 a0 = *(const float4*)(alphas + o * 128 + oct * 8);
        const float4 a1 = *(const float4*)(alphas + o * 128 + oct * 8 + 4);
        bf16x8 v;
        v[0]=(bf16)a0.x; v[1]=(bf16)a0.y; v[2]=(bf16)a0.z; v[3]=(bf16)a0.w;
        v[4]=(bf16)a1.x; v[5]=(bf16)a1.y; v[6]=(bf16)a1.z; v[7]=(bf16)a1.w;
        *(bf16x8*)(lds + o * LDSA_STRIDE + oct * 16) = v;
    }

    // ---- stage x[b, :, h2, :] (fp32 -> bf16) into X4 layout [k>>2][n*4+(k&3)] ----
    const float* xrow = x + ((size_t)b * 128 * 16384) + (size_t)h2 * 128;
    #pragma unroll
    for (int it = 0; it < 4; ++it) {
        const int p  = it * 256 + t;
        const int q  = p >> 5;            // k-quad index 0..31
        const int n0 = (p & 31) * 4;      // column base
        const float4 xv0 = *(const float4*)(xrow + (size_t)(4*q + 0) * 16384 + n0);
        const float4 xv1 = *(const float4*)(xrow + (size_t)(4*q + 1) * 16384 + n0);
        const float4 xv2 = *(const float4*)(xrow + (size_t)(4*q + 2) * 16384 + n0);
        const float4 xv3 = *(const float4*)(xrow + (size_t)(4*q + 3) * 16384 + n0);
        #pragma unroll
        for (int i = 0; i < 4; ++i) {
            bf16x4 v;
            v[0]=(bf16)f4c(xv0,i); v[1]=(bf16)f4c(xv1,i);
            v[2]=(bf16)f4c(xv2,i); v[3]=(bf16)f4c(xv3,i);
            *(bf16x4*)(ldsX + q * 1024 + (n0 + i) * 8) = v;
        }
    }

    __syncthreads();

    // ---- MFMA: D[o][n] = sum_j A[o][j] * X[j][n] ----
    const int l   = t & 63;
    const int wv  = t >> 6;    // wave 0..3 owns n-slice [wv*32, wv*32+32)
    const int g   = l >> 4;    // lane quadrant
    const int lr  = l & 15;
    const int wsl = wv * 32;

    f32x4 acc[8][2];
    #pragma unroll
    for (int mf = 0; mf < 8; ++mf)
        #pragma unroll
        for (int nf = 0; nf < 2; ++nf)
            acc[mf][nf] = (f32x4){0.f, 0.f, 0.f, 0.f};

    #pragma unroll
    for (int ks = 0; ks < 4; ++ks) {
        const int kb = ks * 32;
        // A fragments: 8 contiguous bf16 at j = kb + g*8 (sigma_A(g,v) = g*8+v)
        bf16x8 af[8];
        #pragma unroll
        for (int mf = 0; mf < 8; ++mf)
            af[mf] = *(const bf16x8*)(lds + (mf * 16 + lr) * LDSA_STRIDE + (kb + g * 8) * 2);
        // B fragments: two b64s from interleaved-4 rows -> same sigma (g*8+v)
        bf16x8 bv[2];
        #pragma unroll
        for (int nf = 0; nf < 2; ++nf) {
            const int q0 = (kb >> 2) + g * 2;
            const int n  = wsl + nf * 16 + lr;
            const bf16x4 lo = *(const bf16x4*)(ldsX + q0 * 1024 + n * 8);
            const bf16x4 hi = *(const bf16x4*)(ldsX + (q0 + 1) * 1024 + n * 8);
            bv[nf][0]=lo[0]; bv[nf][1]=lo[1]; bv[nf][2]=lo[2]; bv[nf][3]=lo[3];
            bv[nf][4]=hi[0]; bv[nf][5]=hi[1]; bv[nf][6]=hi[2]; bv[nf][7]=hi[3];
        }
        #pragma unroll
        for (int mf = 0; mf < 8; ++mf)
            #pragma unroll
            for (int nf = 0; nf < 2; ++nf)
                acc[mf][nf] = __builtin_amdgcn_mfma_f32_16x16x32_bf16(
                    af[mf], bv[nf], acc[mf][nf], 0, 0, 0);
    }

    // ---- epilogue: store with spatial flip ----
    // C/D layout (m89/m91-verified): col(n) = lane&15, row(m) = (lane>>4)*4 + reg
    const int h = (128 - h2) & 127;
    float* const outb = out + ((size_t)b * 128 * 16384) + (size_t)h * 128;
    #pragma unroll
    for (int mf = 0; mf < 8; ++mf) {
        #pragma unroll
        for (int nf = 0; nf < 2; ++nf) {
            const int w2 = wsl + nf * 16 + lr;
            const int w  = (128 - w2) & 127;
            const int ob = mf * 16 + g * 4;
            #pragma unroll
            for (int r = 0; r < 4; ++r)
                outb[(size_t)(ob + r) * 16384 + w] = acc[mf][nf][r];
        }
    }
}

extern "C" void kernel_launch(void* const* d_in, const int* in_sizes, int n_in,
                              void* d_out, int out_size, void* d_ws, size_t ws_size,
                              hipStream_t stream) {
    const float* x      = (const float*)d_in[0];
    const float* alphas = (const float*)d_in[1];
    // betas (d_in[2]) provably unused: contributes only to Im(y), dropped by real().
    float* out = (float*)d_out;

    dim3 grid(1024);   // one block per (b, h2): 8 * 128
    dim3 block(256);
    hipLaunchKernelGGL(kk_freqmix_kernel, grid, block, 0, stream, x, alphas, out);
}